// Round 9
// baseline (469.997 us; speedup 1.0000x reference)
//
#include <hip/hip_runtime.h>
#include <hip/hip_bf16.h>

#define NN 50000
#define EE 800000
#define GG 64
#define NBUCK 196              // ceil(NN/256)
#define ABLOCKS 125            // edge chunks: 125 x 6400 = 800000
#define CHUNK 6400
#define BCAP 8192              // LDS bucket capacity (mean 4096, sd ~64)

typedef __attribute__((ext_vector_type(8))) short bf16x8;
typedef __attribute__((ext_vector_type(4))) float f32x4;

// ---- bf16 helpers ----
__device__ __forceinline__ float bflo(unsigned u) { return __uint_as_float(u << 16); }
__device__ __forceinline__ float bfhi(unsigned u) { return __uint_as_float(u & 0xffff0000u); }
__device__ __forceinline__ float b2f(unsigned short s) { return __uint_as_float(((unsigned)s) << 16); }
__device__ __forceinline__ unsigned short f2bf(float f) {
    __hip_bfloat16 h = __float2bfloat16(f);
    union { __hip_bfloat16 h; unsigned short u; } cv; cv.h = h; return cv.u;
}

// -------------------------------------------------------------------------
// Detector (verified r2-r8): flags[0]=fp32? flags[1]=int64?
// -------------------------------------------------------------------------
__global__ void detect_kernel(const unsigned* __restrict__ xw,
                              const unsigned* __restrict__ eiw,
                              int* __restrict__ flags) {
    __shared__ int s_cnt, s_nz;
    if (threadIdx.x == 0) { s_cnt = 0; s_nz = 0; }
    __syncthreads();
    int cnt = 0;
    for (int i = threadIdx.x; i < 4096; i += 256) {
        unsigned w = xw[(size_t)i * 711];
        unsigned elo = (w >> 7) & 0xFF;
        if (elo >= 100 && elo <= 140) cnt++;
    }
    int nz = 0;
    for (int i = threadIdx.x; i < 1024; i += 256) {
        unsigned w = eiw[(size_t)i * 1560 + 1];
        if (w != 0) nz++;
    }
    atomicAdd(&s_cnt, cnt);
    atomicAdd(&s_nz, nz);
    __syncthreads();
    if (threadIdx.x == 0) {
        flags[0] = (s_cnt < 3600) ? 1 : 0;
        flags[1] = (s_nz  < 8)    ? 1 : 0;
    }
}

// -------------------------------------------------------------------------
// Mega prep kernel: blocks [0,3125) convert x; [3125,3674) convert weights;
// [3674,3799) bucket_count; [3799,3831) zero pmxL+psum (131072 B).
// All branches depend only on flags (written by detect).
// -------------------------------------------------------------------------
struct WPtrs { const void* p[15]; };

__global__ __launch_bounds__(256) void prep_kernel(const void* __restrict__ xsrc,
                                                   const unsigned* __restrict__ eiw,
                                                   WPtrs wp,
                                                   unsigned short* __restrict__ arena,
                                                   int* __restrict__ counts,
                                                   uint4* __restrict__ zero_region,
                                                   const int* __restrict__ flags) {
    const int b = blockIdx.x;
    const int tid = threadIdx.x;
    const int isF32 = flags[0];

    if (b < 3125) {
        // ---- convert x: float4 -> 4 bf16 (uint2) ----
        const int total4 = NN * 128 / 4;   // 1,600,000
        for (int i = b * 256 + tid; i < total4; i += 800000) {
            uint2 o;
            if (isF32) {
                float4 f = ((const float4*)xsrc)[i];
                o.x = (unsigned)f2bf(f.x) | ((unsigned)f2bf(f.y) << 16);
                o.y = (unsigned)f2bf(f.z) | ((unsigned)f2bf(f.w) << 16);
            } else {
                o = ((const uint2*)xsrc)[i];
            }
            ((uint2*)arena)[i] = o;
        }
    } else if (b < 3674) {
        // ---- convert weights ----
        const int cnt[15] = {16384,128,16384, 16384,128,16384, 16384,128,16384,
                             32768,128,8192,64,640,10};
        const int dst[15] = {19200000,19232768,19216384, 19232896,19265664,19249280,
                             19265792,19298560,19282176,
                             19298688,19331456,19331584,19339776,19339840,19340480};
        const int total = 140490;
        int i = (b - 3125) * 256 + tid;
        if (i < total) {
            int seg = 0, base = 0;
            while (i - base >= cnt[seg]) { base += cnt[seg]; ++seg; }
            int off = i - base;
            const void* s = wp.p[seg];
            arena[dst[seg] + off] =
                isF32 ? f2bf(((const float*)s)[off]) : ((const unsigned short*)s)[off];
        }
    } else if (b < 3799) {
        // ---- bucket_count ----
        __shared__ int hist[256];
        hist[tid] = 0;
        __syncthreads();
        const int i64 = flags[1];
        const int e0 = (b - 3674) * CHUNK;
        for (int it = 0; it < CHUNK / 256; ++it) {
            int e = e0 + it * 256 + tid;
            int d = (int)(i64 ? eiw[(size_t)2 * (EE + e)] : eiw[EE + e]);
            atomicAdd(&hist[d >> 8], 1);
        }
        __syncthreads();
        counts[(b - 3674) * 256 + tid] = hist[tid];
    } else {
        // ---- zero pool accumulators: 32 blocks x 256 x 16 B = 131072 B ----
        zero_region[(b - 3799) * 256 + tid] = (uint4){0, 0, 0, 0};
    }
}

// -------------------------------------------------------------------------
// CSR build via 2-level bucket sort (verified r6-r8).
// -------------------------------------------------------------------------
__global__ __launch_bounds__(256) void bucket_offsets(const int* __restrict__ counts,
                                                      int* __restrict__ offsets,
                                                      int* __restrict__ bucket_base) {
    __shared__ int s[256];
    const int t = threadIdx.x;
    int col = 0;
    for (int b = 0; b < ABLOCKS; ++b) col += counts[b * 256 + t];
    s[t] = col;
    __syncthreads();
    for (int d = 1; d < 256; d <<= 1) {
        int x = (t >= d) ? s[t - d] : 0;
        __syncthreads();
        s[t] += x;
        __syncthreads();
    }
    int base = s[t] - col;
    bucket_base[t] = base;
    if (t == 255) bucket_base[256] = s[255];
    int run = base;
    for (int b = 0; b < ABLOCKS; ++b) {
        offsets[b * 256 + t] = run;
        run += counts[b * 256 + t];
    }
}

__global__ __launch_bounds__(256) void bucket_scatter(const unsigned* __restrict__ eiw,
                                                      const int* __restrict__ offsets,
                                                      unsigned* __restrict__ packed,
                                                      const int* __restrict__ flags) {
    __shared__ int cur[256];
    cur[threadIdx.x] = offsets[blockIdx.x * 256 + threadIdx.x];
    __syncthreads();
    int i64 = flags[1];
    int e0 = blockIdx.x * CHUNK;
    for (int it = 0; it < CHUNK / 256; ++it) {
        int e = e0 + it * 256 + threadIdx.x;
        int s = (int)(i64 ? eiw[(size_t)2 * e]        : eiw[e]);
        int d = (int)(i64 ? eiw[(size_t)2 * (EE + e)] : eiw[EE + e]);
        int pos = atomicAdd(&cur[d >> 8], 1);
        packed[pos] = ((unsigned)s << 8) | (unsigned)(d & 255);
    }
}

__global__ __launch_bounds__(256) void bucket_sort(const unsigned* __restrict__ packed,
                                                   const int* __restrict__ bucket_base,
                                                   int* __restrict__ csr_src,
                                                   int* __restrict__ row_ptr) {
    __shared__ unsigned sbuf[BCAP];
    __shared__ int hist[256];
    __shared__ int cur[256];
    const int t = threadIdx.x;
    const int b = blockIdx.x;
    const int lo = bucket_base[b];
    int n = bucket_base[b + 1] - lo;
    if (n > BCAP) n = BCAP;

    hist[t] = 0;
    __syncthreads();
    for (int i = t; i < n; i += 256) {
        unsigned p = packed[lo + i];
        sbuf[i] = p;
        atomicAdd(&hist[p & 255], 1);
    }
    __syncthreads();
    int v = hist[t];
    __shared__ int s[256];
    s[t] = v;
    __syncthreads();
    for (int d = 1; d < 256; d <<= 1) {
        int x = (t >= d) ? s[t - d] : 0;
        __syncthreads();
        s[t] += x;
        __syncthreads();
    }
    int start = s[t] - v;
    int node = b * 256 + t;
    if (node < NN) row_ptr[node] = lo + start;
    if (b == 0 && t == 0) row_ptr[NN] = EE;
    cur[t] = start;
    __syncthreads();
    for (int i = t; i < n; i += 256) {
        unsigned p = sbuf[i];
        int pos = atomicAdd(&cur[p & 255], 1);
        csr_src[lo + pos] = (int)(p >> 8);
    }
}

// -------------------------------------------------------------------------
// Fused conv layer v2: gather (quarter-wave rows) + MFMA GEMM + relu + pool.
// Block = 256 thr (4 waves), 64-row tile.
// Phase 1: each quarter-wave (16 lanes) owns one row at a time (4 serial
//   rows per wave); uint4 loads = full 256 B neighbor row per batch lane-set;
//   8 neighbors in flight. Critical path: 8 latency batches/wave (was 16).
// Phase 2: r4-verified MFMA GEMM; agg A-frags from LDS, x A-frags + W B-frags
//   from global.
// Phase 3: per-column run-wise pool -> device atomics (uint max / fp32 add).
// -------------------------------------------------------------------------
__global__ __launch_bounds__(256) void conv_fused(const unsigned short* __restrict__ hin,
                                                  const int* __restrict__ row_ptr,
                                                  const int* __restrict__ csr_src,
                                                  const unsigned short* __restrict__ Wrel,
                                                  const unsigned short* __restrict__ Wroot,
                                                  const unsigned short* __restrict__ brel,
                                                  const unsigned* __restrict__ bw,
                                                  unsigned* __restrict__ pmx,      // this layer's [64][128]
                                                  float* __restrict__ psum,        // cross-layer [64][128]
                                                  unsigned short* __restrict__ outb,
                                                  void* __restrict__ outG,
                                                  const int* __restrict__ flags) {
    __shared__ __align__(16) unsigned short tile[64][136];   // agg, then h (17 KB)
    __shared__ int sbatch[64];

    const int tid  = threadIdx.x;
    const int wv   = tid >> 6;
    const int lane = tid & 63;
    const int qw   = lane >> 4;     // quarter-wave 0..3
    const int l16  = lane & 15;
    const int m0   = blockIdx.x * 64;
    const uint4* h16 = (const uint4*)hin;   // 16 uint4 per 128-ch row

    // ---- Phase 1: gather, one row per quarter-wave, 4 serial ----
    #pragma unroll
    for (int i = 0; i < 4; ++i) {
        const int lr = wv * 16 + i * 4 + qw;
        const int r  = m0 + lr;
        float a[8];
        #pragma unroll
        for (int c = 0; c < 8; ++c) a[c] = 0.f;
        if (r < NN) {
            int jb = row_ptr[r], je = row_ptr[r + 1];
            int j = jb;
            for (; j + 8 <= je; j += 8) {
                uint4 u[8];
                #pragma unroll
                for (int q = 0; q < 8; ++q)
                    u[q] = h16[(size_t)csr_src[j + q] * 16 + l16];
                #pragma unroll
                for (int q = 0; q < 8; ++q) {
                    a[0] += bflo(u[q].x); a[1] += bfhi(u[q].x);
                    a[2] += bflo(u[q].y); a[3] += bfhi(u[q].y);
                    a[4] += bflo(u[q].z); a[5] += bfhi(u[q].z);
                    a[6] += bflo(u[q].w); a[7] += bfhi(u[q].w);
                }
            }
            for (; j < je; ++j) {
                uint4 u = h16[(size_t)csr_src[j] * 16 + l16];
                a[0] += bflo(u.x); a[1] += bfhi(u.x);
                a[2] += bflo(u.y); a[3] += bfhi(u.y);
                a[4] += bflo(u.z); a[5] += bfhi(u.z);
                a[6] += bflo(u.w); a[7] += bfhi(u.w);
            }
        }
        uint4 o;
        o.x = (unsigned)f2bf(a[0]) | ((unsigned)f2bf(a[1]) << 16);
        o.y = (unsigned)f2bf(a[2]) | ((unsigned)f2bf(a[3]) << 16);
        o.z = (unsigned)f2bf(a[4]) | ((unsigned)f2bf(a[5]) << 16);
        o.w = (unsigned)f2bf(a[6]) | ((unsigned)f2bf(a[7]) << 16);
        *(uint4*)&tile[lr][l16 * 8] = o;   // 272 B row stride, 16 B aligned
    }
    __syncthreads();

    // ---- Phase 2: MFMA GEMM ----
    const int mrow = lane & 15;
    const int quad = lane >> 4;
    const int r    = m0 + wv * 16 + mrow;
    const bool rv  = r < NN;

    f32x4 acc[8];
    #pragma unroll
    for (int n = 0; n < 8; ++n) acc[n] = (f32x4){0.f, 0.f, 0.f, 0.f};

    #pragma unroll
    for (int kk = 0; kk < 8; ++kk) {
        const unsigned short* Bs = (kk < 4) ? Wrel : Wroot;
        const int kc = (kk & 3) * 32 + quad * 8;
        bf16x8 a;
        if (kk < 4) {
            a = *(const bf16x8*)&tile[wv * 16 + mrow][kc];
        } else {
            a = (bf16x8){0, 0, 0, 0, 0, 0, 0, 0};
            if (rv) a = *(const bf16x8*)(hin + (size_t)r * 128 + kc);
        }
        #pragma unroll
        for (int n = 0; n < 8; ++n) {
            bf16x8 b = *(const bf16x8*)(Bs + (size_t)(n * 16 + mrow) * 128 + kc);
            acc[n] = __builtin_amdgcn_mfma_f32_16x16x32_bf16(a, b, acc[n], 0, 0, 0);
        }
    }

    const int isF32 = flags[0];
    #pragma unroll
    for (int n = 0; n < 8; ++n) {
        const int col = n * 16 + mrow;
        const float bias = b2f(brel[col]);
        #pragma unroll
        for (int i = 0; i < 4; ++i) {
            const int lrow = wv * 16 + quad * 4 + i;
            const int row  = m0 + lrow;
            if (row < NN) {
                float v = fmaxf(acc[n][i] + bias, 0.f);
                unsigned short bv = f2bf(v);
                outb[(size_t)row * 128 + col] = bv;
                tile[lrow][col] = bv;
                if (outG) {
                    size_t o = (size_t)640 + (size_t)row * 128 + col;
                    if (isF32) ((float*)outG)[o] = __uint_as_float((unsigned)bv << 16);
                    else       ((unsigned short*)outG)[o] = bv;
                }
            }
        }
    }

    // ---- Phase 3: pool over the tile ----
    const int i64 = flags[1];
    if (tid < 64) {
        int rr = m0 + tid;
        sbatch[tid] = (rr < NN) ? (int)(i64 ? bw[(size_t)2 * rr] : bw[rr]) : -1;
    }
    __syncthreads();
    if (tid < 128) {
        const int col = tid;
        int curg = -1;
        float mx = 0.f, sm = 0.f;
        for (int rr = 0; rr < 64; ++rr) {
            int g = sbatch[rr];
            if (g != curg) {
                if (curg >= 0) {
                    atomicMax(&pmx[curg * 128 + col], __float_as_uint(mx));
                    unsafeAtomicAdd(&psum[curg * 128 + col], sm);
                }
                curg = g; mx = 0.f; sm = 0.f;
            }
            if (g >= 0) {
                float v = b2f(tile[rr][col]);
                mx = fmaxf(mx, v);
                sm += v;
            }
        }
        if (curg >= 0) {
            atomicMax(&pmx[curg * 128 + col], __float_as_uint(mx));
            unsafeAtomicAdd(&psum[curg * 128 + col], sm);
        }
    }
}

// -------------------------------------------------------------------------
// MLP head: ge from pmxL (3 layers) + psum/cnt; graph_emb emit; 3-layer MLP.
// -------------------------------------------------------------------------
__global__ __launch_bounds__(256) void mlp_kernel(const unsigned* __restrict__ pmxL,
                                                  const float* __restrict__ psum,
                                                  const unsigned* __restrict__ bw,
                                                  const unsigned short* __restrict__ W1,
                                                  const unsigned short* __restrict__ b1,
                                                  const unsigned short* __restrict__ W2,
                                                  const unsigned short* __restrict__ b2,
                                                  const unsigned short* __restrict__ W3,
                                                  const unsigned short* __restrict__ b3,
                                                  void* __restrict__ out,
                                                  const int* __restrict__ flags) {
    int g = blockIdx.x;
    int t = threadIdx.x;
    int isF32 = flags[0];
    int i64 = flags[1];
    __shared__ float sge[256];
    __shared__ float sz1[128];
    __shared__ float sz2[64];

    int lo = 0, hi = NN;
    while (lo < hi) {
        int mid = (lo + hi) >> 1;
        int bv = (int)(i64 ? bw[(size_t)2 * mid] : bw[mid]);
        if (bv < g) lo = mid + 1; else hi = mid;
    }
    int start = lo;
    hi = NN;
    while (lo < hi) {
        int mid = (lo + hi) >> 1;
        int bv = (int)(i64 ? bw[(size_t)2 * mid] : bw[mid]);
        if (bv < g + 1) lo = mid + 1; else hi = mid;
    }
    int cnt = lo - start;

    float v;
    if (t < 128) {
        v = __uint_as_float(pmxL[g * 128 + t])
          + __uint_as_float(pmxL[8192 + g * 128 + t])
          + __uint_as_float(pmxL[16384 + g * 128 + t]);
    } else {
        v = psum[g * 128 + (t - 128)] / fmaxf((float)cnt, 1.f);
    }
    sge[t] = v;
    size_t geo = (size_t)640 + (size_t)NN * 128 + (size_t)g * 256 + t;
    if (isF32) ((float*)out)[geo] = v;
    else       ((unsigned short*)out)[geo] = f2bf(v);
    __syncthreads();

    if (t < 128) {
        float acc = b2f(b1[t]);
        for (int k = 0; k < 256; ++k) acc = fmaf(sge[k], b2f(W1[t * 256 + k]), acc);
        sz1[t] = fmaxf(acc, 0.f);
    }
    __syncthreads();
    if (t < 64) {
        float acc = b2f(b2[t]);
        for (int k = 0; k < 128; ++k) acc = fmaf(sz1[k], b2f(W2[t * 128 + k]), acc);
        sz2[t] = fmaxf(acc, 0.f);
    }
    __syncthreads();
    if (t < 10) {
        float acc = b2f(b3[t]);
        for (int k = 0; k < 64; ++k) acc = fmaf(sz2[k], b2f(W3[t * 64 + k]), acc);
        size_t o = (size_t)g * 10 + t;
        if (isF32) ((float*)out)[o] = acc;
        else       ((unsigned short*)out)[o] = f2bf(acc);
    }
}

// ---- bf16 arena element offsets ----
#define XBF_OFF   0            // x, then h3
#define HA_OFF    6400000      // h1
#define HB_OFF    12800000     // h2
#define WR1_OFF   19200000
#define WO1_OFF   19216384
#define BR1_OFF   19232768
#define WR2_OFF   19232896
#define WO2_OFF   19249280
#define BR2_OFF   19265664
#define WR3_OFF   19265792
#define WO3_OFF   19282176
#define BR3_OFF   19298560
#define W1_OFF    19298688
#define B1_OFF    19331456
#define W2_OFF    19331584
#define B2_OFF    19339776
#define W3_OFF    19339840
#define B3_OFF    19340480
#define ARENA_END 19340490

extern "C" void kernel_launch(void* const* d_in, const int* in_sizes, int n_in,
                              void* d_out, int out_size, void* d_ws, size_t ws_size,
                              hipStream_t stream) {
    unsigned short* arena = (unsigned short*)d_ws;
    size_t intBase = ((size_t)ARENA_END * 2 + 255) & ~(size_t)255;
    char* ib = (char*)d_ws + intBase;
    int*      row_ptr = (int*)ib;                            //   200,064 B
    int*      csr_src = (int*)(ib + 200064);                 // 3,200,000 B
    unsigned* packed  = (unsigned*)(ib + 3400064);           // 3,200,000 B
    int*      counts  = (int*)(ib + 6600064);                //   128,000 B
    int*      offsets = (int*)(ib + 6728064);                //   128,000 B
    int*      bbase   = (int*)(ib + 6856064);                //     1,028 B
    unsigned* pmxL    = (unsigned*)(ib + 6857344);           //    98,304 B [3][64][128]
    float*    psum    = (float*)(ib + 6955648);              //    32,768 B [64][128]
    int*      flags   = (int*)(ib + 6988416);                //         8 B

    const unsigned* eiw = (const unsigned*)d_in[1];
    const unsigned* bw  = (const unsigned*)d_in[2];
    dim3 blk(256);

    detect_kernel<<<1, 256, 0, stream>>>((const unsigned*)d_in[0], eiw, flags);

    // Mega prep: convert x + convert weights + bucket_count + zero pools.
    WPtrs wp;
    for (int i = 0; i < 15; ++i) wp.p[i] = d_in[3 + i];
    prep_kernel<<<3831, blk, 0, stream>>>(d_in[0], eiw, wp, arena, counts,
                                          (uint4*)pmxL, flags);

    // CSR build
    bucket_offsets<<<1, blk, 0, stream>>>(counts, offsets, bbase);
    bucket_scatter<<<ABLOCKS, blk, 0, stream>>>(eiw, offsets, packed, flags);
    bucket_sort<<<NBUCK, blk, 0, stream>>>(packed, bbase, csr_src, row_ptr);

    const int convGrid = (NN + 63) / 64;      // 782

    // ---- Layer 1: x(X) -> h1(HA) ----
    conv_fused<<<convGrid, blk, 0, stream>>>(arena + XBF_OFF, row_ptr, csr_src,
                                             arena + WR1_OFF, arena + WO1_OFF, arena + BR1_OFF,
                                             bw, pmxL, psum, arena + HA_OFF, nullptr, flags);
    // ---- Layer 2: h1(HA) -> h2(HB) ----
    conv_fused<<<convGrid, blk, 0, stream>>>(arena + HA_OFF, row_ptr, csr_src,
                                             arena + WR2_OFF, arena + WO2_OFF, arena + BR2_OFF,
                                             bw, pmxL + 8192, psum, arena + HB_OFF, nullptr, flags);
    // ---- Layer 3: h2(HB) -> h3(X slot) + node_embs to d_out ----
    conv_fused<<<convGrid, blk, 0, stream>>>(arena + HB_OFF, row_ptr, csr_src,
                                             arena + WR3_OFF, arena + WO3_OFF, arena + BR3_OFF,
                                             bw, pmxL + 16384, psum, arena + XBF_OFF, d_out, flags);

    mlp_kernel<<<GG, blk, 0, stream>>>(pmxL, psum, bw,
                                       arena + W1_OFF, arena + B1_OFF,
                                       arena + W2_OFF, arena + B2_OFF,
                                       arena + W3_OFF, arena + B3_OFF, d_out, flags);
}

// Round 11
// 390.036 us; speedup vs baseline: 1.2050x; 1.2050x over previous
//
#include <hip/hip_runtime.h>
#include <hip/hip_bf16.h>

#define NN 50000
#define EE 800000
#define GG 64
#define NBUCK 196              // ceil(NN/256)
#define ABLOCKS 125            // edge chunks: 125 x 6400 = 800000
#define CHUNK 6400
#define BCAP 8192              // LDS bucket capacity (mean 4096, sd ~64)

typedef __attribute__((ext_vector_type(8))) short bf16x8;
typedef __attribute__((ext_vector_type(4))) float f32x4;

// ---- bf16 helpers ----
__device__ __forceinline__ float bflo(unsigned u) { return __uint_as_float(u << 16); }
__device__ __forceinline__ float bfhi(unsigned u) { return __uint_as_float(u & 0xffff0000u); }
__device__ __forceinline__ float b2f(unsigned short s) { return __uint_as_float(((unsigned)s) << 16); }
__device__ __forceinline__ unsigned short f2bf(float f) {
    __hip_bfloat16 h = __float2bfloat16(f);
    union { __hip_bfloat16 h; unsigned short u; } cv; cv.h = h; return cv.u;
}

// -------------------------------------------------------------------------
// Detector (verified r2-r9): flags[0]=fp32? flags[1]=int64?
// -------------------------------------------------------------------------
__global__ void detect_kernel(const unsigned* __restrict__ xw,
                              const unsigned* __restrict__ eiw,
                              int* __restrict__ flags) {
    __shared__ int s_cnt, s_nz;
    if (threadIdx.x == 0) { s_cnt = 0; s_nz = 0; }
    __syncthreads();
    int cnt = 0;
    for (int i = threadIdx.x; i < 4096; i += 256) {
        unsigned w = xw[(size_t)i * 711];
        unsigned elo = (w >> 7) & 0xFF;
        if (elo >= 100 && elo <= 140) cnt++;
    }
    int nz = 0;
    for (int i = threadIdx.x; i < 1024; i += 256) {
        unsigned w = eiw[(size_t)i * 1560 + 1];
        if (w != 0) nz++;
    }
    atomicAdd(&s_cnt, cnt);
    atomicAdd(&s_nz, nz);
    __syncthreads();
    if (threadIdx.x == 0) {
        flags[0] = (s_cnt < 3600) ? 1 : 0;
        flags[1] = (s_nz  < 8)    ? 1 : 0;
    }
}

// -------------------------------------------------------------------------
// Mega prep: [0,3125) convert x; [3125,3674) convert weights;
// [3674,3799) bucket_count; [3799,4055) zero pool slices (1 MiB).
// -------------------------------------------------------------------------
struct WPtrs { const void* p[15]; };

__global__ __launch_bounds__(256) void prep_kernel(const void* __restrict__ xsrc,
                                                   const unsigned* __restrict__ eiw,
                                                   WPtrs wp,
                                                   unsigned short* __restrict__ arena,
                                                   int* __restrict__ counts,
                                                   uint4* __restrict__ zero_region,
                                                   const int* __restrict__ flags) {
    const int b = blockIdx.x;
    const int tid = threadIdx.x;
    const int isF32 = flags[0];

    if (b < 3125) {
        const int total4 = NN * 128 / 4;   // 1,600,000
        for (int i = b * 256 + tid; i < total4; i += 800000) {
            uint2 o;
            if (isF32) {
                float4 f = ((const float4*)xsrc)[i];
                o.x = (unsigned)f2bf(f.x) | ((unsigned)f2bf(f.y) << 16);
                o.y = (unsigned)f2bf(f.z) | ((unsigned)f2bf(f.w) << 16);
            } else {
                o = ((const uint2*)xsrc)[i];
            }
            ((uint2*)arena)[i] = o;
        }
    } else if (b < 3674) {
        const int cnt[15] = {16384,128,16384, 16384,128,16384, 16384,128,16384,
                             32768,128,8192,64,640,10};
        const int dst[15] = {19200000,19232768,19216384, 19232896,19265664,19249280,
                             19265792,19298560,19282176,
                             19298688,19331456,19331584,19339776,19339840,19340480};
        const int total = 140490;
        int i = (b - 3125) * 256 + tid;
        if (i < total) {
            int seg = 0, base = 0;
            while (i - base >= cnt[seg]) { base += cnt[seg]; ++seg; }
            int off = i - base;
            const void* s = wp.p[seg];
            arena[dst[seg] + off] =
                isF32 ? f2bf(((const float*)s)[off]) : ((const unsigned short*)s)[off];
        }
    } else if (b < 3799) {
        __shared__ int hist[256];
        hist[tid] = 0;
        __syncthreads();
        const int i64 = flags[1];
        const int e0 = (b - 3674) * CHUNK;
        for (int it = 0; it < CHUNK / 256; ++it) {
            int e = e0 + it * 256 + tid;
            int d = (int)(i64 ? eiw[(size_t)2 * (EE + e)] : eiw[EE + e]);
            atomicAdd(&hist[d >> 8], 1);
        }
        __syncthreads();
        counts[(b - 3674) * 256 + tid] = hist[tid];
    } else {
        // zero pool accumulators: 256 blocks x 256 thr x 16 B = 1,048,576 B
        zero_region[(b - 3799) * 256 + tid] = (uint4){0, 0, 0, 0};
    }
}

// -------------------------------------------------------------------------
// CSR build via 2-level bucket sort (verified r6-r9).
// -------------------------------------------------------------------------
__global__ __launch_bounds__(256) void bucket_offsets(const int* __restrict__ counts,
                                                      int* __restrict__ offsets,
                                                      int* __restrict__ bucket_base) {
    __shared__ int s[256];
    const int t = threadIdx.x;
    int col = 0;
    for (int b = 0; b < ABLOCKS; ++b) col += counts[b * 256 + t];
    s[t] = col;
    __syncthreads();
    for (int d = 1; d < 256; d <<= 1) {
        int x = (t >= d) ? s[t - d] : 0;
        __syncthreads();
        s[t] += x;
        __syncthreads();
    }
    int base = s[t] - col;
    bucket_base[t] = base;
    if (t == 255) bucket_base[256] = s[255];
    int run = base;
    for (int b = 0; b < ABLOCKS; ++b) {
        offsets[b * 256 + t] = run;
        run += counts[b * 256 + t];
    }
}

__global__ __launch_bounds__(256) void bucket_scatter(const unsigned* __restrict__ eiw,
                                                      const int* __restrict__ offsets,
                                                      unsigned* __restrict__ packed,
                                                      const int* __restrict__ flags) {
    __shared__ int cur[256];
    cur[threadIdx.x] = offsets[blockIdx.x * 256 + threadIdx.x];
    __syncthreads();
    int i64 = flags[1];
    int e0 = blockIdx.x * CHUNK;
    for (int it = 0; it < CHUNK / 256; ++it) {
        int e = e0 + it * 256 + threadIdx.x;
        int s = (int)(i64 ? eiw[(size_t)2 * e]        : eiw[e]);
        int d = (int)(i64 ? eiw[(size_t)2 * (EE + e)] : eiw[EE + e]);
        int pos = atomicAdd(&cur[d >> 8], 1);
        packed[pos] = ((unsigned)s << 8) | (unsigned)(d & 255);
    }
}

__global__ __launch_bounds__(256) void bucket_sort(const unsigned* __restrict__ packed,
                                                   const int* __restrict__ bucket_base,
                                                   int* __restrict__ csr_src,
                                                   int* __restrict__ row_ptr) {
    __shared__ unsigned sbuf[BCAP];
    __shared__ int hist[256];
    __shared__ int cur[256];
    const int t = threadIdx.x;
    const int b = blockIdx.x;
    const int lo = bucket_base[b];
    int n = bucket_base[b + 1] - lo;
    if (n > BCAP) n = BCAP;

    hist[t] = 0;
    __syncthreads();
    for (int i = t; i < n; i += 256) {
        unsigned p = packed[lo + i];
        sbuf[i] = p;
        atomicAdd(&hist[p & 255], 1);
    }
    __syncthreads();
    int v = hist[t];
    __shared__ int s[256];
    s[t] = v;
    __syncthreads();
    for (int d = 1; d < 256; d <<= 1) {
        int x = (t >= d) ? s[t - d] : 0;
        __syncthreads();
        s[t] += x;
        __syncthreads();
    }
    int start = s[t] - v;
    int node = b * 256 + t;
    if (node < NN) row_ptr[node] = lo + start;
    if (b == 0 && t == 0) row_ptr[NN] = EE;
    cur[t] = start;
    __syncthreads();
    for (int i = t; i < n; i += 256) {
        unsigned p = sbuf[i];
        int pos = atomicAdd(&cur[p & 255], 1);
        csr_src[lo + pos] = (int)(p >> 8);
    }
}

// -------------------------------------------------------------------------
// Fused conv v3.1: 16-row tile, 3125 blocks (NN/16 exactly, no bounds checks).
// Phase 1 (gather, r8-proven pattern): wave serially does 4 rows; half-waves
//   take even/odd neighbors of the SAME row (uniform bounds); uint2 8-deep.
// Phase 2 (MFMA): wave owns cols [wv*32,+32) -> acc[2].
//   *** RACE FIX (r10 post-mortem): all 4 waves read ALL tile columns as agg
//   A-frags, but each wave's epilogue overwrites its column slice with h.
//   A __syncthreads() between the MFMA loop and the epilogue orders
//   all-reads-before-any-write. ***
// Phase 3 (pool): run-wise per column; atomics into slice blockIdx&7.
// -------------------------------------------------------------------------
__global__ __launch_bounds__(256, 8) void conv_fused(const unsigned short* __restrict__ hin,
                                                     const int* __restrict__ row_ptr,
                                                     const int* __restrict__ csr_src,
                                                     const unsigned short* __restrict__ Wrel,
                                                     const unsigned short* __restrict__ Wroot,
                                                     const unsigned short* __restrict__ brel,
                                                     const unsigned* __restrict__ bw,
                                                     unsigned* __restrict__ pmx,   // layer's [8][64][128]
                                                     float* __restrict__ psum,     // [8][64][128]
                                                     unsigned short* __restrict__ outb,
                                                     void* __restrict__ outG,
                                                     const int* __restrict__ flags) {
    __shared__ __align__(16) unsigned short tile[16][136];   // 4.25 KB
    __shared__ int sbatch[16];

    const int tid  = threadIdx.x;
    const int wv   = tid >> 6;
    const int lane = tid & 63;
    const int half = lane >> 5;
    const int l32  = lane & 31;
    const int m0   = blockIdx.x * 16;
    const uint2* h8 = (const uint2*)hin;       // 32 uint2 per 128-ch row

    // ---- Phase 1: gather 4 serial rows per wave ----
    for (int i = 0; i < 4; ++i) {
        const int lr = wv * 4 + i;
        const int r  = m0 + lr;
        float ax = 0.f, ay = 0.f, az = 0.f, aw = 0.f;
        int jb = row_ptr[r], je = row_ptr[r + 1];
        int j = jb + half;
        for (; j + 14 < je; j += 16) {
            uint2 u[8];
            #pragma unroll
            for (int q = 0; q < 8; ++q)
                u[q] = h8[(size_t)csr_src[j + 2 * q] * 32 + l32];
            #pragma unroll
            for (int q = 0; q < 8; ++q) {
                ax += bflo(u[q].x); ay += bfhi(u[q].x);
                az += bflo(u[q].y); aw += bfhi(u[q].y);
            }
        }
        for (; j + 6 < je; j += 8) {
            uint2 u[4];
            #pragma unroll
            for (int q = 0; q < 4; ++q)
                u[q] = h8[(size_t)csr_src[j + 2 * q] * 32 + l32];
            #pragma unroll
            for (int q = 0; q < 4; ++q) {
                ax += bflo(u[q].x); ay += bfhi(u[q].x);
                az += bflo(u[q].y); aw += bfhi(u[q].y);
            }
        }
        for (; j < je; j += 2) {
            uint2 u = h8[(size_t)csr_src[j] * 32 + l32];
            ax += bflo(u.x); ay += bfhi(u.x);
            az += bflo(u.y); aw += bfhi(u.y);
        }
        ax += __shfl_xor(ax, 32);
        ay += __shfl_xor(ay, 32);
        az += __shfl_xor(az, 32);
        aw += __shfl_xor(aw, 32);
        if (half == 0) {
            uint2 o;
            o.x = (unsigned)f2bf(ax) | ((unsigned)f2bf(ay) << 16);
            o.y = (unsigned)f2bf(az) | ((unsigned)f2bf(aw) << 16);
            *(uint2*)&tile[lr][l32 * 4] = o;
        }
    }
    __syncthreads();

    // ---- Phase 2: MFMA GEMM, wave owns a 32-col slice ----
    const int mrow = lane & 15;
    const int quad = lane >> 4;
    const int r    = m0 + mrow;

    f32x4 acc[2];
    acc[0] = (f32x4){0.f, 0.f, 0.f, 0.f};
    acc[1] = (f32x4){0.f, 0.f, 0.f, 0.f};

    #pragma unroll
    for (int kk = 0; kk < 8; ++kk) {
        const unsigned short* Bs = (kk < 4) ? Wrel : Wroot;
        const int kc = (kk & 3) * 32 + quad * 8;
        bf16x8 a;
        if (kk < 4) a = *(const bf16x8*)&tile[mrow][kc];
        else        a = *(const bf16x8*)(hin + (size_t)r * 128 + kc);
        #pragma unroll
        for (int n = 0; n < 2; ++n) {
            const int col0 = (wv * 2 + n) * 16;
            bf16x8 b = *(const bf16x8*)(Bs + (size_t)(col0 + mrow) * 128 + kc);
            acc[n] = __builtin_amdgcn_mfma_f32_16x16x32_bf16(a, b, acc[n], 0, 0, 0);
        }
    }

    __syncthreads();   // RACE FIX: all agg A-frag reads complete before h overwrites tile

    const int isF32 = flags[0];
    #pragma unroll
    for (int n = 0; n < 2; ++n) {
        const int col = (wv * 2 + n) * 16 + mrow;
        const float bias = b2f(brel[col]);
        #pragma unroll
        for (int i = 0; i < 4; ++i) {
            const int lrow = quad * 4 + i;
            const int row  = m0 + lrow;
            float v = fmaxf(acc[n][i] + bias, 0.f);
            unsigned short bv = f2bf(v);
            outb[(size_t)row * 128 + col] = bv;
            tile[lrow][col] = bv;
            if (outG) {
                size_t o = (size_t)640 + (size_t)row * 128 + col;
                if (isF32) ((float*)outG)[o] = __uint_as_float((unsigned)bv << 16);
                else       ((unsigned short*)outG)[o] = bv;
            }
        }
    }

    // ---- Phase 3: pool over the 16-row tile into slice blockIdx&7 ----
    const int i64 = flags[1];
    if (tid < 16) {
        int rr = m0 + tid;
        sbatch[tid] = (int)(i64 ? bw[(size_t)2 * rr] : bw[rr]);
    }
    __syncthreads();
    if (tid < 128) {
        const int col = tid;
        const int slice = blockIdx.x & 7;
        int curg = sbatch[0];
        float mx = 0.f, sm = 0.f;
        for (int rr = 0; rr < 16; ++rr) {
            int g = sbatch[rr];
            if (g != curg) {
                atomicMax(&pmx[(slice * GG + curg) * 128 + col], __float_as_uint(mx));
                unsafeAtomicAdd(&psum[(slice * GG + curg) * 128 + col], sm);
                curg = g; mx = 0.f; sm = 0.f;
            }
            float v = b2f(tile[rr][col]);
            mx = fmaxf(mx, v);
            sm += v;
        }
        atomicMax(&pmx[(slice * GG + curg) * 128 + col], __float_as_uint(mx));
        unsafeAtomicAdd(&psum[(slice * GG + curg) * 128 + col], sm);
    }
}

// -------------------------------------------------------------------------
// MLP head: ge from sliced pmxL (3 layers x 8 slices) + psum slices / cnt;
// graph_emb emit; 3-layer MLP. One block per graph.
// -------------------------------------------------------------------------
__global__ __launch_bounds__(256) void mlp_kernel(const unsigned* __restrict__ pmxL,
                                                  const float* __restrict__ psum,
                                                  const unsigned* __restrict__ bw,
                                                  const unsigned short* __restrict__ W1,
                                                  const unsigned short* __restrict__ b1,
                                                  const unsigned short* __restrict__ W2,
                                                  const unsigned short* __restrict__ b2,
                                                  const unsigned short* __restrict__ W3,
                                                  const unsigned short* __restrict__ b3,
                                                  void* __restrict__ out,
                                                  const int* __restrict__ flags) {
    int g = blockIdx.x;
    int t = threadIdx.x;
    int isF32 = flags[0];
    int i64 = flags[1];
    __shared__ float sge[256];
    __shared__ float sz1[128];
    __shared__ float sz2[64];

    int lo = 0, hi = NN;
    while (lo < hi) {
        int mid = (lo + hi) >> 1;
        int bv = (int)(i64 ? bw[(size_t)2 * mid] : bw[mid]);
        if (bv < g) lo = mid + 1; else hi = mid;
    }
    int start = lo;
    hi = NN;
    while (lo < hi) {
        int mid = (lo + hi) >> 1;
        int bv = (int)(i64 ? bw[(size_t)2 * mid] : bw[mid]);
        if (bv < g + 1) lo = mid + 1; else hi = mid;
    }
    int cnt = lo - start;

    float v;
    if (t < 128) {
        v = 0.f;
        #pragma unroll
        for (int L = 0; L < 3; ++L) {
            float m = 0.f;
            #pragma unroll
            for (int s = 0; s < 8; ++s)
                m = fmaxf(m, __uint_as_float(pmxL[((L * 8 + s) * GG + g) * 128 + t]));
            v += m;
        }
    } else {
        float sm = 0.f;
        #pragma unroll
        for (int s = 0; s < 8; ++s) sm += psum[(s * GG + g) * 128 + (t - 128)];
        v = sm / fmaxf((float)cnt, 1.f);
    }
    sge[t] = v;
    size_t geo = (size_t)640 + (size_t)NN * 128 + (size_t)g * 256 + t;
    if (isF32) ((float*)out)[geo] = v;
    else       ((unsigned short*)out)[geo] = f2bf(v);
    __syncthreads();

    if (t < 128) {
        float acc = b2f(b1[t]);
        for (int k = 0; k < 256; ++k) acc = fmaf(sge[k], b2f(W1[t * 256 + k]), acc);
        sz1[t] = fmaxf(acc, 0.f);
    }
    __syncthreads();
    if (t < 64) {
        float acc = b2f(b2[t]);
        for (int k = 0; k < 128; ++k) acc = fmaf(sz1[k], b2f(W2[t * 128 + k]), acc);
        sz2[t] = fmaxf(acc, 0.f);
    }
    __syncthreads();
    if (t < 10) {
        float acc = b2f(b3[t]);
        for (int k = 0; k < 64; ++k) acc = fmaf(sz2[k], b2f(W3[t * 64 + k]), acc);
        size_t o = (size_t)g * 10 + t;
        if (isF32) ((float*)out)[o] = acc;
        else       ((unsigned short*)out)[o] = f2bf(acc);
    }
}

// ---- bf16 arena element offsets ----
#define XBF_OFF   0            // x, then h3
#define HA_OFF    6400000      // h1
#define HB_OFF    12800000     // h2
#define WR1_OFF   19200000
#define WO1_OFF   19216384
#define BR1_OFF   19232768
#define WR2_OFF   19232896
#define WO2_OFF   19249280
#define BR2_OFF   19265664
#define WR3_OFF   19265792
#define WO3_OFF   19282176
#define BR3_OFF   19298560
#define W1_OFF    19298688
#define B1_OFF    19331456
#define W2_OFF    19331584
#define B2_OFF    19339776
#define W3_OFF    19339840
#define B3_OFF    19340480
#define ARENA_END 19340490

extern "C" void kernel_launch(void* const* d_in, const int* in_sizes, int n_in,
                              void* d_out, int out_size, void* d_ws, size_t ws_size,
                              hipStream_t stream) {
    unsigned short* arena = (unsigned short*)d_ws;
    size_t intBase = ((size_t)ARENA_END * 2 + 255) & ~(size_t)255;
    char* ib = (char*)d_ws + intBase;
    int*      row_ptr = (int*)ib;                            //   200,064 B
    int*      csr_src = (int*)(ib + 200064);                 // 3,200,000 B
    unsigned* packed  = (unsigned*)(ib + 3400064);           // 3,200,000 B
    int*      counts  = (int*)(ib + 6600064);                //   128,000 B
    int*      offsets = (int*)(ib + 6728064);                //   128,000 B
    int*      bbase   = (int*)(ib + 6856064);                //     1,028 B (pad to 6,857,344)
    unsigned* pmxL    = (unsigned*)(ib + 6857344);           //   786,432 B [3][8][64][128]
    float*    psum    = (float*)(ib + 7643776);              //   262,144 B [8][64][128]
    int*      flags   = (int*)(ib + 7905920);                //         8 B

    const unsigned* eiw = (const unsigned*)d_in[1];
    const unsigned* bw  = (const unsigned*)d_in[2];
    dim3 blk(256);

    detect_kernel<<<1, 256, 0, stream>>>((const unsigned*)d_in[0], eiw, flags);

    // Mega prep: convert x + weights + bucket_count + zero pool slices (1 MiB).
    WPtrs wp;
    for (int i = 0; i < 15; ++i) wp.p[i] = d_in[3 + i];
    prep_kernel<<<4055, blk, 0, stream>>>(d_in[0], eiw, wp, arena, counts,
                                          (uint4*)pmxL, flags);

    // CSR build
    bucket_offsets<<<1, blk, 0, stream>>>(counts, offsets, bbase);
    bucket_scatter<<<ABLOCKS, blk, 0, stream>>>(eiw, offsets, packed, flags);
    bucket_sort<<<NBUCK, blk, 0, stream>>>(packed, bbase, csr_src, row_ptr);

    const int convGrid = NN / 16;             // 3125

    // ---- Layer 1: x(X) -> h1(HA) ----
    conv_fused<<<convGrid, blk, 0, stream>>>(arena + XBF_OFF, row_ptr, csr_src,
                                             arena + WR1_OFF, arena + WO1_OFF, arena + BR1_OFF,
                                             bw, pmxL, psum, arena + HA_OFF, nullptr, flags);
    // ---- Layer 2: h1(HA) -> h2(HB) ----
    conv_fused<<<convGrid, blk, 0, stream>>>(arena + HA_OFF, row_ptr, csr_src,
                                             arena + WR2_OFF, arena + WO2_OFF, arena + BR2_OFF,
                                             bw, pmxL + 65536, psum, arena + HB_OFF, nullptr, flags);
    // ---- Layer 3: h2(HB) -> h3(X slot) + node_embs to d_out ----
    conv_fused<<<convGrid, blk, 0, stream>>>(arena + HB_OFF, row_ptr, csr_src,
                                             arena + WR3_OFF, arena + WO3_OFF, arena + BR3_OFF,
                                             bw, pmxL + 131072, psum, arena + XBF_OFF, d_out, flags);

    mlp_kernel<<<GG, blk, 0, stream>>>(pmxL, psum, bw,
                                       arena + W1_OFF, arena + B1_OFF,
                                       arena + W2_OFF, arena + B2_OFF,
                                       arena + W3_OFF, arena + B3_OFF, d_out, flags);
}